// Round 5
// baseline (216.052 us; speedup 1.0000x reference)
//
#include <hip/hip_runtime.h>
#include <hip/hip_bf16.h>
#include <math.h>

#define HW 4096
#define LN_EPS 1e-5f

typedef _Float16 half4v __attribute__((ext_vector_type(4)));
typedef _Float16 half8v __attribute__((ext_vector_type(8)));
typedef float float4v __attribute__((ext_vector_type(4)));

#if __has_builtin(__builtin_amdgcn_exp2f)
#define EXP2F(x) __builtin_amdgcn_exp2f(x)
#else
#define EXP2F(x) exp2f(x)
#endif

__device__ __forceinline__ half4v lo4(half8v v) { return __builtin_shufflevector(v, v, 0, 1, 2, 3); }
__device__ __forceinline__ half4v hi4(half8v v) { return __builtin_shufflevector(v, v, 4, 5, 6, 7); }

// perm32 (V positions only): stored slot p holds j = (p&3) + 4*((p>>3)&3) + 16*((p>>2)&1);
// b128 at slot quad*8 yields j = {quad*4+0..3, 16+quad*4+0..3} = the k-fragments of the
// two 16x16x16 PV MFMAs.
__device__ __forceinline__ int inv32(int d) {
    return (d & 3) + (((d >> 4) & 1) << 2) + (((d >> 2) & 3) << 3);
}
// y swizzle: element (pos, o) stored at pos*256 + ((o>>3 ^ (pos&7))<<3) + (o&7)
__device__ __forceinline__ int yswz(int p, int o) {
    return ((((o >> 3) ^ (p & 7)) << 3) | (o & 7));
}

// ---------------- kernel 1: weights fp32->f16 (+Q pre-scale) and pos bilinear ----------
__global__ void k_prep(const float* __restrict__ wq, const float* __restrict__ wp,
                       const float* __restrict__ pb,
                       _Float16* __restrict__ wqh, _Float16* __restrict__ wph,
                       float* __restrict__ pos) {
    const float qs = 0.17677669529663687f * 1.4426950408889634f; // scale * log2(e)
    int i = blockIdx.x * 256 + threadIdx.x;
    if (i < 49152) { // wq: 768*512/8 chunks; rows <256 (chunks <16384) pre-scaled
        float s = (i < 16384) ? qs : 1.0f;
        float4v a = *(const float4v*)(wq + i * 8);
        float4v b = *(const float4v*)(wq + i * 8 + 4);
        half8v h;
        #pragma unroll
        for (int k = 0; k < 4; k++) { h[k] = (_Float16)(a[k] * s); h[4 + k] = (_Float16)(b[k] * s); }
        *(half8v*)(wqh + i * 8) = h;
    } else if (i < 65536) { // wp: 512*256/8 chunks
        int j = i - 49152;
        float4v a = *(const float4v*)(wp + j * 8);
        float4v b = *(const float4v*)(wp + j * 8 + 4);
        half8v h;
        #pragma unroll
        for (int k = 0; k < 4; k++) { h[k] = (_Float16)a[k]; h[4 + k] = (_Float16)b[k]; }
        *(half8v*)(wph + j * 8) = h;
    } else { // pos bilinear 16->64, times log2(e)
        int j = i - 65536;
        int h = j >> 12, p = j & 4095, y = p >> 6, x = p & 63;
        float sy = y * 0.25f - 0.375f, sx = x * 0.25f - 0.375f;
        float fy = floorf(sy), fx = floorf(sx);
        float wy = sy - fy, wx = sx - fx;
        int y0 = (int)fy, x0 = (int)fx;
        int y1 = y0 + 1 < 15 ? y0 + 1 : 15;
        int x1 = x0 + 1 < 15 ? x0 + 1 : 15;
        y0 = y0 > 0 ? y0 : 0;
        x0 = x0 > 0 ? x0 : 0;
        const float* src = pb + h * 256;
        float v = (1.f - wy) * ((1.f - wx) * src[y0 * 16 + x0] + wx * src[y0 * 16 + x1]) +
                  wy * ((1.f - wx) * src[y1 * 16 + x0] + wx * src[y1 * 16 + x1]);
        pos[j] = v * 1.4426950408889634f;
    }
}

// ---------------- kernel 2: transpose x [512][4096] f32 -> xt [4096][512] f16 ----------
__global__ __launch_bounds__(256) void k_xt(const float* __restrict__ x,
                                            _Float16* __restrict__ xt) {
    __shared__ _Float16 tile[64][65];
    int c0 = (blockIdx.x >> 6) * 64;
    int p0 = (blockIdx.x & 63) * 64;
    int t = threadIdx.x, w = t >> 6, lane = t & 63;
    #pragma unroll
    for (int r = 0; r < 16; r++)
        tile[w * 16 + r][lane] = (_Float16)x[(c0 + w * 16 + r) * HW + p0 + lane];
    __syncthreads();
    #pragma unroll
    for (int r = 0; r < 16; r++)
        xt[(p0 + w * 16 + r) * 512 + c0 + lane] = tile[lane][w * 16 + r];
}

// ---------------- kernel 3: QKV GEMM, LDS-free (A=xt rows, B=w rows, both b128) -------
// Outputs: qa/ka [h][pos][d] identity; va [h*32+d][posperm32]
__global__ __launch_bounds__(256) void k_qkv(const _Float16* __restrict__ wqh,
                                             const _Float16* __restrict__ xt,
                                             _Float16* __restrict__ qa,
                                             _Float16* __restrict__ ka,
                                             _Float16* __restrict__ va) {
    int n0 = (blockIdx.x >> 6) * 64;  // out-channel tile base (12 tiles)
    int p0 = (blockIdx.x & 63) * 64;  // position tile base
    int t = threadIdx.x, w = t >> 6, lane = t & 63, quad = lane >> 4, l16 = lane & 15;

    const _Float16* aptr = xt + (p0 + w * 16 + l16) * 512 + quad * 8;
    const _Float16* bptr = wqh + (n0 + l16) * 512 + quad * 8;

    float4v acc[4] = {};
    #pragma unroll 4
    for (int kc = 0; kc < 16; kc++) {
        half8v a = *(const half8v*)(aptr + kc * 32);
        #pragma unroll
        for (int nt = 0; nt < 4; nt++) {
            half8v b = *(const half8v*)(bptr + nt * 16 * 512 + kc * 32);
            acc[nt] = __builtin_amdgcn_mfma_f32_16x16x32_f16(a, b, acc[nt], 0, 0, 0);
        }
    }
    // D: row=quad*4+r -> pos, col=l16 -> out-channel
    #pragma unroll
    for (int nt = 0; nt < 4; nt++) {
        int o = n0 + nt * 16 + l16;
        #pragma unroll
        for (int r = 0; r < 4; r++) {
            int p = p0 + w * 16 + quad * 4 + r;
            _Float16 v = (_Float16)acc[nt][r];
            if (o < 256) {
                qa[(o >> 5) * 131072 + p * 32 + (o & 31)] = v;
            } else if (o < 512) {
                ka[((o - 256) >> 5) * 131072 + p * 32 + (o & 31)] = v;
            } else {
                va[(o - 512) * HW + (p & ~31) + inv32(p & 31)] = v;
            }
        }
    }
}

// ---------------- kernel 4: flash attention, XCD-pinned heads, j-split x4 -------------
// h = blockIdx & 7 -> all blocks of a head share one XCD's L2 (512KB K/V resident).
// S^T = K.Q^T via one 16x16x32 MFMA per 16-j group; C-layout == P's A-layout for PV.
__global__ __launch_bounds__(256, 4) void k_attn(const _Float16* __restrict__ qa,
                                                 const _Float16* __restrict__ ka,
                                                 const _Float16* __restrict__ va,
                                                 const float* __restrict__ pos,
                                                 _Float16* __restrict__ yh) {
    __shared__ float smem[4096]; // [0,4096): per-wave pos quarter; reused for O/l reduce
    int h = blockIdx.x & 7;
    int q0 = (blockIdx.x >> 3) * 16;
    int t = threadIdx.x, w = t >> 6, lane = t & 63, quad = lane >> 4, l16 = lane & 15;
    int jb = w * 1024;

    // stage this wave's pos quarter into LDS (wave-private, no barrier needed)
    float* posl = smem + w * 1024;
    {
        const float* ph = pos + h * HW + jb;
        #pragma unroll
        for (int rr = 0; rr < 4; rr++)
            *(float4v*)(posl + rr * 256 + lane * 4) = *(const float4v*)(ph + rr * 256 + lane * 4);
    }

    half8v qf = *(const half8v*)(qa + h * 131072 + (q0 + l16) * 32 + quad * 8);
    const _Float16* kptr = ka + h * 131072 + l16 * 32 + quad * 8;
    const _Float16* vptr0 = va + h * 131072 + l16 * HW + quad * 8;
    const _Float16* vptr1 = vptr0 + 16 * HW;

    float4v o0 = {}, o1 = {};
    float lsum = 0.f;
    const float4v zero = {0.f, 0.f, 0.f, 0.f};

    for (int j0 = jb; j0 < jb + 1024; j0 += 32) {
        half8v kf0 = *(const half8v*)(kptr + j0 * 32);          // rows j0+l16
        half8v kf1 = *(const half8v*)(kptr + (j0 + 16) * 32);   // rows j0+16+l16
        half8v vf0 = *(const half8v*)(vptr0 + j0);              // d = l16
        half8v vf1 = *(const half8v*)(vptr1 + j0);              // d = 16+l16
        float4v pb0 = *(const float4v*)(posl + (j0 - jb) + quad * 4);
        float4v pb1 = *(const float4v*)(posl + (j0 - jb) + 16 + quad * 4);

        // S^T sub-tiles (rows j, col query); scale*log2e folded into Q.
        float4v s0 = __builtin_amdgcn_mfma_f32_16x16x32_f16(kf0, qf, zero, 0, 0, 0);
        float4v s1 = __builtin_amdgcn_mfma_f32_16x16x32_f16(kf1, qf, zero, 0, 0, 0);

        float e0 = EXP2F(s0[0] + pb0[0]);
        float e1 = EXP2F(s0[1] + pb0[1]);
        float e2 = EXP2F(s0[2] + pb0[2]);
        float e3 = EXP2F(s0[3] + pb0[3]);
        float e4 = EXP2F(s1[0] + pb1[0]);
        float e5 = EXP2F(s1[1] + pb1[1]);
        float e6 = EXP2F(s1[2] + pb1[2]);
        float e7 = EXP2F(s1[3] + pb1[3]);
        lsum += ((e0 + e1) + (e2 + e3)) + ((e4 + e5) + (e6 + e7));

        half4v pa0, pa1;
        pa0[0] = (_Float16)e0; pa0[1] = (_Float16)e1;
        pa0[2] = (_Float16)e2; pa0[3] = (_Float16)e3;
        pa1[0] = (_Float16)e4; pa1[1] = (_Float16)e5;
        pa1[2] = (_Float16)e6; pa1[3] = (_Float16)e7;

        o0 = __builtin_amdgcn_mfma_f32_16x16x16f16(pa0, lo4(vf0), o0, 0, 0, 0);
        o0 = __builtin_amdgcn_mfma_f32_16x16x16f16(pa1, hi4(vf0), o0, 0, 0, 0);
        o1 = __builtin_amdgcn_mfma_f32_16x16x16f16(pa0, lo4(vf1), o1, 0, 0, 0);
        o1 = __builtin_amdgcn_mfma_f32_16x16x16f16(pa1, hi4(vf1), o1, 0, 0, 0);
    }
    // per-wave l reduction (lane's partial is for query=l16)
    lsum += __shfl_xor(lsum, 16, 64);
    lsum += __shfl_xor(lsum, 32, 64);
    __syncthreads(); // pos-staging reads done chip-wide before smem reuse
    // stash partials: po(w,q,d) = smem[w*528 + q*33 + d]; pl(w,q) = smem[2112+w*16+q]
    #pragma unroll
    for (int r = 0; r < 4; r++) {
        smem[w * 528 + (quad * 4 + r) * 33 + l16] = o0[r];
        smem[w * 528 + (quad * 4 + r) * 33 + 16 + l16] = o1[r];
    }
    if (quad == 0) smem[2112 + w * 16 + l16] = lsum;
    __syncthreads();
    // combine 4 j-quarters: thread t -> (q = t>>4, d = t&15 and d+16)
    int q = t >> 4, d = t & 15;
    float v0 = 0.f, v1 = 0.f, l = 0.f;
    #pragma unroll
    for (int ww = 0; ww < 4; ww++) {
        v0 += smem[ww * 528 + q * 33 + d];
        v1 += smem[ww * 528 + q * 33 + 16 + d];
        l += smem[2112 + ww * 16 + q];
    }
    float inv = 1.f / l;
    int p = q0 + q;
    yh[p * 256 + yswz(p, h * 32 + d)] = (_Float16)(v0 * inv);
    yh[p * 256 + yswz(p, h * 32 + 16 + d)] = (_Float16)(v1 * inv);
}

// ---------------- kernel 5: proj GEMM + bias + residual + LayerNorm (16 waves) ----------
__global__ __launch_bounds__(1024) void k_proj_ln(const _Float16* __restrict__ wph,
                                                  const _Float16* __restrict__ yh,
                                                  const float* __restrict__ x,
                                                  const float* __restrict__ b_proj,
                                                  const float* __restrict__ gamma,
                                                  const float* __restrict__ beta,
                                                  float* __restrict__ out) {
    __shared__ __attribute__((aligned(16))) _Float16 ys[16 * 256]; // mirrors swizzled global
    __shared__ float red[2][16][17];
    int p0 = blockIdx.x * 16;
    int t = threadIdx.x, w = t >> 6, lane = t & 63, quad = lane >> 4, l16 = lane & 15;
    if (t < 512) *(half8v*)&ys[t * 8] = *(const half8v*)&yh[p0 * 256 + t * 8];
    __syncthreads();
    float4v acc[2] = {};
    #pragma unroll
    for (int kc = 0; kc < 8; kc++) {
        int u = (kc * 4 + quad) ^ (l16 & 7);
        half8v b = *(const half8v*)&ys[l16 * 256 + u * 8];
        #pragma unroll
        for (int mt = 0; mt < 2; mt++) {
            half8v a = *(const half8v*)&wph[(w * 32 + mt * 16 + l16) * 256 + kc * 32 + quad * 8];
            acc[mt] = __builtin_amdgcn_mfma_f32_16x16x32_f16(a, b, acc[mt], 0, 0, 0);
        }
    }
    int p = p0 + l16;
    float sum = 0.f, sumsq = 0.f;
    #pragma unroll
    for (int mt = 0; mt < 2; mt++)
        #pragma unroll
        for (int r = 0; r < 4; r++) {
            int c = w * 32 + mt * 16 + quad * 4 + r;
            float v = acc[mt][r] + b_proj[c] + x[c * HW + p];
            acc[mt][r] = v;
            sum += v;
            sumsq += v * v;
        }
    sum += __shfl_xor(sum, 16, 64);
    sum += __shfl_xor(sum, 32, 64);
    sumsq += __shfl_xor(sumsq, 16, 64);
    sumsq += __shfl_xor(sumsq, 32, 64);
    if (quad == 0) { red[0][w][l16] = sum; red[1][w][l16] = sumsq; }
    __syncthreads();
    float s0 = 0.f, s1 = 0.f;
    #pragma unroll
    for (int ww = 0; ww < 16; ww++) { s0 += red[0][ww][l16]; s1 += red[1][ww][l16]; }
    float mean = s0 * (1.f / 512.f);
    float var = s1 * (1.f / 512.f) - mean * mean;
    float rstd = rsqrtf(var + LN_EPS);
    #pragma unroll
    for (int mt = 0; mt < 2; mt++)
        #pragma unroll
        for (int r = 0; r < 4; r++) {
            int c = w * 32 + mt * 16 + quad * 4 + r;
            out[c * HW + p] = (acc[mt][r] - mean) * rstd * gamma[c] + beta[c];
        }
}

extern "C" void kernel_launch(void* const* d_in, const int* in_sizes, int n_in,
                              void* d_out, int out_size, void* d_ws, size_t ws_size,
                              hipStream_t stream) {
    const float* x      = (const float*)d_in[0];
    const float* w_qkv  = (const float*)d_in[1];
    const float* w_proj = (const float*)d_in[2];
    const float* b_proj = (const float*)d_in[3];
    const float* pos_b  = (const float*)d_in[4];
    const float* gamma  = (const float*)d_in[5];
    const float* beta   = (const float*)d_in[6];
    char* ws = (char*)d_ws;
    _Float16* xt  = (_Float16*)(ws);              // 4096*512*2   = 4194304
    _Float16* qa  = (_Float16*)(ws + 4194304);    // 8*4096*32*2  = 2097152
    _Float16* ka  = (_Float16*)(ws + 6291456);    // 2097152
    _Float16* va  = (_Float16*)(ws + 8388608);    // 2097152
    _Float16* yh  = (_Float16*)(ws + 10485760);   // 4096*256*2   = 2097152
    float*    pos = (float*)   (ws + 12582912);   // 8*4096*4     = 131072
    _Float16* wqh = (_Float16*)(ws + 12714240);   // 768*512*2    = 786432
    _Float16* wph = (_Float16*)(ws + 13500672);   // 512*256*2    = 262144

    k_prep<<<384, 256, 0, stream>>>(w_qkv, w_proj, pos_b, wqh, wph, pos);
    k_xt<<<512, 256, 0, stream>>>(x, xt);
    k_qkv<<<768, 256, 0, stream>>>(wqh, xt, qa, ka, va);
    k_attn<<<2048, 256, 0, stream>>>(qa, ka, va, pos, yh);
    k_proj_ln<<<256, 1024, 0, stream>>>(wph, yh, x, b_proj, gamma, beta, (float*)d_out);
}

// Round 6
// 151.032 us; speedup vs baseline: 1.4305x; 1.4305x over previous
//
#include <hip/hip_runtime.h>
#include <hip/hip_bf16.h>
#include <math.h>

#define HW 4096
#define LN_EPS 1e-5f

typedef _Float16 half4v __attribute__((ext_vector_type(4)));
typedef _Float16 half8v __attribute__((ext_vector_type(8)));
typedef float float4v __attribute__((ext_vector_type(4)));

#if __has_builtin(__builtin_amdgcn_exp2f)
#define EXP2F(x) __builtin_amdgcn_exp2f(x)
#else
#define EXP2F(x) exp2f(x)
#endif

__device__ __forceinline__ half4v lo4(half8v v) { return __builtin_shufflevector(v, v, 0, 1, 2, 3); }
__device__ __forceinline__ half4v hi4(half8v v) { return __builtin_shufflevector(v, v, 4, 5, 6, 7); }

// ---------------- kernel 1: weights fp32->f16 (+Q pre-scale) and pos bilinear ----------
__global__ void k_prep(const float* __restrict__ wq, const float* __restrict__ wp,
                       const float* __restrict__ pb,
                       _Float16* __restrict__ wqh, _Float16* __restrict__ wph,
                       float* __restrict__ pos) {
    const float qs = 0.17677669529663687f * 1.4426950408889634f; // scale * log2(e)
    int i = blockIdx.x * 256 + threadIdx.x;
    if (i < 49152) { // wq: 768*512/8 chunks; rows <256 (chunks <16384) pre-scaled
        float s = (i < 16384) ? qs : 1.0f;
        float4v a = *(const float4v*)(wq + i * 8);
        float4v b = *(const float4v*)(wq + i * 8 + 4);
        half8v h;
        #pragma unroll
        for (int k = 0; k < 4; k++) { h[k] = (_Float16)(a[k] * s); h[4 + k] = (_Float16)(b[k] * s); }
        *(half8v*)(wqh + i * 8) = h;
    } else if (i < 65536) { // wp: 512*256/8 chunks
        int j = i - 49152;
        float4v a = *(const float4v*)(wp + j * 8);
        float4v b = *(const float4v*)(wp + j * 8 + 4);
        half8v h;
        #pragma unroll
        for (int k = 0; k < 4; k++) { h[k] = (_Float16)a[k]; h[4 + k] = (_Float16)b[k]; }
        *(half8v*)(wph + j * 8) = h;
    } else { // pos bilinear 16->64, times log2(e)
        int j = i - 65536;
        int h = j >> 12, p = j & 4095, y = p >> 6, x = p & 63;
        float sy = y * 0.25f - 0.375f, sx = x * 0.25f - 0.375f;
        float fy = floorf(sy), fx = floorf(sx);
        float wy = sy - fy, wx = sx - fx;
        int y0 = (int)fy, x0 = (int)fx;
        int y1 = y0 + 1 < 15 ? y0 + 1 : 15;
        int x1 = x0 + 1 < 15 ? x0 + 1 : 15;
        y0 = y0 > 0 ? y0 : 0;
        x0 = x0 > 0 ? x0 : 0;
        const float* src = pb + h * 256;
        float v = (1.f - wy) * ((1.f - wx) * src[y0 * 16 + x0] + wx * src[y0 * 16 + x1]) +
                  wy * ((1.f - wx) * src[y1 * 16 + x0] + wx * src[y1 * 16 + x1]);
        pos[j] = v * 1.4426950408889634f;
    }
}

// ---------------- kernel 2: transpose x [512][4096] f32 -> xt [4096][512] f16 ----------
__global__ __launch_bounds__(256) void k_xt(const float* __restrict__ x,
                                            _Float16* __restrict__ xt) {
    __shared__ _Float16 tile[64][65];
    int c0 = (blockIdx.x >> 6) * 64;
    int p0 = (blockIdx.x & 63) * 64;
    int t = threadIdx.x, w = t >> 6, lane = t & 63;
    #pragma unroll
    for (int r = 0; r < 16; r++)
        tile[w * 16 + r][lane] = (_Float16)x[(c0 + w * 16 + r) * HW + p0 + lane];
    __syncthreads();
    #pragma unroll
    for (int r = 0; r < 16; r++)
        xt[(p0 + w * 16 + r) * 512 + c0 + lane] = tile[lane][w * 16 + r];
}

// ---------------- kernel 3: QKV GEMM, LDS-free, 64n x 128p tiles ----------------------
// Outputs: qa [h][q][d] row-major; ka/va as raw MFMA fragment streams per 16-j window:
//   ka: [h][j>>4][lane=(d>>3)*16+(j&15)][idx=d&7]           (A-frag stream for QK)
//   va: [h][j>>4][lane=((j>>2)&3)*16+(d&15)][idx=(d>>4)*4+(j&3)]  (B-frag stream for PV)
__global__ __launch_bounds__(256) void k_qkv(const _Float16* __restrict__ wqh,
                                             const _Float16* __restrict__ xt,
                                             _Float16* __restrict__ qa,
                                             _Float16* __restrict__ ka,
                                             _Float16* __restrict__ va) {
    int n0 = (blockIdx.x >> 5) * 64;   // 12 n-tiles
    int p0 = (blockIdx.x & 31) * 128;  // 32 p-tiles
    int t = threadIdx.x, w = t >> 6, lane = t & 63, quad = lane >> 4, l16 = lane & 15;

    const _Float16* aptr0 = xt + (p0 + w * 16 + l16) * 512 + quad * 8;
    const _Float16* aptr1 = aptr0 + 64 * 512;
    const _Float16* bptr = wqh + (n0 + l16) * 512 + quad * 8;

    float4v acc[2][4] = {};
    #pragma unroll 4
    for (int kc = 0; kc < 16; kc++) {
        half8v a0 = *(const half8v*)(aptr0 + kc * 32);
        half8v a1 = *(const half8v*)(aptr1 + kc * 32);
        #pragma unroll
        for (int nt = 0; nt < 4; nt++) {
            half8v b = *(const half8v*)(bptr + nt * 16 * 512 + kc * 32);
            acc[0][nt] = __builtin_amdgcn_mfma_f32_16x16x32_f16(a0, b, acc[0][nt], 0, 0, 0);
            acc[1][nt] = __builtin_amdgcn_mfma_f32_16x16x32_f16(a1, b, acc[1][nt], 0, 0, 0);
        }
    }
    // D: row=quad*4+r -> pos, col=l16 -> out-channel
    #pragma unroll
    for (int ps = 0; ps < 2; ps++) {
        #pragma unroll
        for (int nt = 0; nt < 4; nt++) {
            int o = n0 + nt * 16 + l16;
            #pragma unroll
            for (int r = 0; r < 4; r++) {
                int p = p0 + ps * 64 + w * 16 + quad * 4 + r;
                _Float16 v = (_Float16)acc[ps][nt][r];
                if (o < 256) {
                    qa[(o >> 5) * 131072 + p * 32 + (o & 31)] = v;
                } else if (o < 512) {
                    int oc = o - 256, hh = oc >> 5, d = oc & 31;
                    ka[hh * 131072 + (p >> 4) * 512 + ((d >> 3) * 16 + (p & 15)) * 8 + (d & 7)] = v;
                } else {
                    int oc = o - 512, hh = oc >> 5, d = oc & 31;
                    va[hh * 131072 + (p >> 4) * 512 + (((p >> 2) & 3) * 16 + (d & 15)) * 8 +
                       (d >> 4) * 4 + (p & 3)] = v;
                }
            }
        }
    }
}

// ---------------- kernel 4: flash attention, LDS-staged K/V shared by 4 waves ----------
// grid 512 = 8 heads x 2 j-halves x 32 q-blocks; block = 128 q (4 waves x 32 q).
// K/V tiles (64 j) double-buffered in LDS, reg-prefetched, ONE barrier per tile.
// Writes unnormalized fp32 O-partials + l-partials per j-half.
__global__ __launch_bounds__(256) void k_attn(const _Float16* __restrict__ qa,
                                              const _Float16* __restrict__ ka,
                                              const _Float16* __restrict__ va,
                                              const float* __restrict__ pos,
                                              float* __restrict__ op,
                                              float* __restrict__ lp) {
    __shared__ __attribute__((aligned(16))) _Float16 kbuf[2][2048];
    __shared__ __attribute__((aligned(16))) _Float16 vbuf[2][2048];
    __shared__ __attribute__((aligned(16))) float posl[2048];
    int h = blockIdx.x & 7;
    int jh = (blockIdx.x >> 3) & 1;
    int qb = blockIdx.x >> 4;
    int t = threadIdx.x, w = t >> 6, lane = t & 63, quad = lane >> 4, l16 = lane & 15;
    int q0 = qb * 128 + w * 32;

    float* opp = op + jh * 1048576;
    float* lpp = lp + jh * 32768;

    { // stage this (head, j-half)'s pos
        const float* ps_ = pos + h * HW + jh * 2048;
        *(float4v*)(posl + t * 8) = *(const float4v*)(ps_ + t * 8);
        *(float4v*)(posl + t * 8 + 4) = *(const float4v*)(ps_ + t * 8 + 4);
    }
    half8v qf0 = *(const half8v*)(qa + h * 131072 + (q0 + l16) * 32 + quad * 8);
    half8v qf1 = *(const half8v*)(qa + h * 131072 + (q0 + 16 + l16) * 32 + quad * 8);

    const _Float16* kg = ka + h * 131072 + jh * 65536;
    const _Float16* vg = va + h * 131072 + jh * 65536;

    half8v kreg = *(const half8v*)(kg + t * 8);
    half8v vreg = *(const half8v*)(vg + t * 8);

    float4v o00 = {}, o01 = {}, o10 = {}, o11 = {};
    float lsum0 = 0.f, lsum1 = 0.f;
    const float4v zero = {0.f, 0.f, 0.f, 0.f};

    for (int tile = 0; tile < 32; tile++) {
        int buf = tile & 1;
        *(half8v*)(kbuf[buf] + t * 8) = kreg;
        *(half8v*)(vbuf[buf] + t * 8) = vreg;
        __syncthreads();
        if (tile + 1 < 32) {
            kreg = *(const half8v*)(kg + (tile + 1) * 2048 + t * 8);
            vreg = *(const half8v*)(vg + (tile + 1) * 2048 + t * 8);
        }
        #pragma unroll
        for (int w16 = 0; w16 < 4; w16++) {
            half8v kf = *(const half8v*)(kbuf[buf] + w16 * 512 + lane * 8);
            half8v vf = *(const half8v*)(vbuf[buf] + w16 * 512 + lane * 8);
            float4v pb = *(const float4v*)(posl + tile * 64 + w16 * 16 + quad * 4);

            float4v s0 = __builtin_amdgcn_mfma_f32_16x16x32_f16(kf, qf0, zero, 0, 0, 0);
            float4v s1 = __builtin_amdgcn_mfma_f32_16x16x32_f16(kf, qf1, zero, 0, 0, 0);

            float e0 = EXP2F(s0[0] + pb[0]);
            float e1 = EXP2F(s0[1] + pb[1]);
            float e2 = EXP2F(s0[2] + pb[2]);
            float e3 = EXP2F(s0[3] + pb[3]);
            float f0 = EXP2F(s1[0] + pb[0]);
            float f1 = EXP2F(s1[1] + pb[1]);
            float f2 = EXP2F(s1[2] + pb[2]);
            float f3 = EXP2F(s1[3] + pb[3]);
            lsum0 += (e0 + e1) + (e2 + e3);
            lsum1 += (f0 + f1) + (f2 + f3);

            half4v pa0, pa1;
            pa0[0] = (_Float16)e0; pa0[1] = (_Float16)e1;
            pa0[2] = (_Float16)e2; pa0[3] = (_Float16)e3;
            pa1[0] = (_Float16)f0; pa1[1] = (_Float16)f1;
            pa1[2] = (_Float16)f2; pa1[3] = (_Float16)f3;

            o00 = __builtin_amdgcn_mfma_f32_16x16x16f16(pa0, lo4(vf), o00, 0, 0, 0);
            o01 = __builtin_amdgcn_mfma_f32_16x16x16f16(pa0, hi4(vf), o01, 0, 0, 0);
            o10 = __builtin_amdgcn_mfma_f32_16x16x16f16(pa1, lo4(vf), o10, 0, 0, 0);
            o11 = __builtin_amdgcn_mfma_f32_16x16x16f16(pa1, hi4(vf), o11, 0, 0, 0);
        }
    }
    // total l per query (sum over quads' j-rows)
    lsum0 += __shfl_xor(lsum0, 16, 64);
    lsum0 += __shfl_xor(lsum0, 32, 64);
    lsum1 += __shfl_xor(lsum1, 16, 64);
    lsum1 += __shfl_xor(lsum1, 32, 64);
    // O partials: D-layout row=quad*4+r -> q, col=l16 -> d
    #pragma unroll
    for (int r = 0; r < 4; r++) {
        int qr = quad * 4 + r;
        int qi0 = q0 + qr, qi1 = q0 + 16 + qr;
        opp[qi0 * 256 + h * 32 + l16] = o00[r];
        opp[qi0 * 256 + h * 32 + 16 + l16] = o01[r];
        opp[qi1 * 256 + h * 32 + l16] = o10[r];
        opp[qi1 * 256 + h * 32 + 16 + l16] = o11[r];
    }
    if (quad == 0) {
        lpp[(q0 + l16) * 8 + h] = lsum0;
        lpp[(q0 + 16 + l16) * 8 + h] = lsum1;
    }
}

// ---------------- kernel 5: combine partials + proj GEMM + residual + LayerNorm --------
__global__ __launch_bounds__(1024) void k_proj_ln(const _Float16* __restrict__ wph,
                                                  const float* __restrict__ op,
                                                  const float* __restrict__ lp,
                                                  const float* __restrict__ x,
                                                  const float* __restrict__ b_proj,
                                                  const float* __restrict__ gamma,
                                                  const float* __restrict__ beta,
                                                  float* __restrict__ out) {
    __shared__ __attribute__((aligned(16))) _Float16 ys[16 * 264];
    __shared__ float red[2][16][17];
    int p0 = blockIdx.x * 16;
    int t = threadIdx.x, w = t >> 6, lane = t & 63, quad = lane >> 4, l16 = lane & 15;
    { // combine j-half partials, normalize, stage to LDS
        int p = t >> 6;          // 0..15
        int cg = (t & 63) * 4;   // 0..252
        int pi = p0 + p;
        float4v a = *(const float4v*)(op + pi * 256 + cg);
        float4v b = *(const float4v*)(op + 1048576 + pi * 256 + cg);
        int hh = cg >> 5;
        float l = lp[pi * 8 + hh] + lp[32768 + pi * 8 + hh];
        float inv = 1.f / l;
        half4v y;
        #pragma unroll
        for (int k = 0; k < 4; k++) y[k] = (_Float16)((a[k] + b[k]) * inv);
        *(half4v*)(ys + p * 264 + cg) = y;
    }
    __syncthreads();
    float4v acc[2] = {};
    #pragma unroll
    for (int kc = 0; kc < 8; kc++) {
        half8v b = *(const half8v*)(ys + l16 * 264 + kc * 32 + quad * 8);
        #pragma unroll
        for (int mt = 0; mt < 2; mt++) {
            half8v a = *(const half8v*)(wph + (w * 32 + mt * 16 + l16) * 256 + kc * 32 + quad * 8);
            acc[mt] = __builtin_amdgcn_mfma_f32_16x16x32_f16(a, b, acc[mt], 0, 0, 0);
        }
    }
    int p = p0 + l16;
    float sum = 0.f, sumsq = 0.f;
    #pragma unroll
    for (int mt = 0; mt < 2; mt++)
        #pragma unroll
        for (int r = 0; r < 4; r++) {
            int c = w * 32 + mt * 16 + quad * 4 + r;
            float v = acc[mt][r] + b_proj[c] + x[c * HW + p];
            acc[mt][r] = v;
            sum += v;
            sumsq += v * v;
        }
    sum += __shfl_xor(sum, 16, 64);
    sum += __shfl_xor(sum, 32, 64);
    sumsq += __shfl_xor(sumsq, 16, 64);
    sumsq += __shfl_xor(sumsq, 32, 64);
    if (quad == 0) { red[0][w][l16] = sum; red[1][w][l16] = sumsq; }
    __syncthreads();
    float s0 = 0.f, s1 = 0.f;
    #pragma unroll
    for (int ww = 0; ww < 16; ww++) { s0 += red[0][ww][l16]; s1 += red[1][ww][l16]; }
    float mean = s0 * (1.f / 512.f);
    float var = s1 * (1.f / 512.f) - mean * mean;
    float rstd = rsqrtf(var + LN_EPS);
    #pragma unroll
    for (int mt = 0; mt < 2; mt++)
        #pragma unroll
        for (int r = 0; r < 4; r++) {
            int c = w * 32 + mt * 16 + quad * 4 + r;
            out[c * HW + p] = (acc[mt][r] - mean) * rstd * gamma[c] + beta[c];
        }
}

extern "C" void kernel_launch(void* const* d_in, const int* in_sizes, int n_in,
                              void* d_out, int out_size, void* d_ws, size_t ws_size,
                              hipStream_t stream) {
    const float* x      = (const float*)d_in[0];
    const float* w_qkv  = (const float*)d_in[1];
    const float* w_proj = (const float*)d_in[2];
    const float* b_proj = (const float*)d_in[3];
    const float* pos_b  = (const float*)d_in[4];
    const float* gamma  = (const float*)d_in[5];
    const float* beta   = (const float*)d_in[6];
    char* ws = (char*)d_ws;
    _Float16* xt  = (_Float16*)(ws);              // 4096*512*2     = 4194304
    _Float16* qa  = (_Float16*)(ws + 4194304);    // 8*4096*32*2    = 2097152
    _Float16* ka  = (_Float16*)(ws + 6291456);    // 2097152
    _Float16* va  = (_Float16*)(ws + 8388608);    // 2097152
    float*    op  = (float*)   (ws + 10485760);   // 2*4096*256*4   = 8388608
    float*    lp  = (float*)   (ws + 18874368);   // 2*4096*8*4     = 262144
    float*    pos = (float*)   (ws + 19136512);   // 8*4096*4       = 131072
    _Float16* wqh = (_Float16*)(ws + 19267584);   // 768*512*2      = 786432
    _Float16* wph = (_Float16*)(ws + 20054016);   // 512*256*2      = 262144

    k_prep<<<384, 256, 0, stream>>>(w_qkv, w_proj, pos_b, wqh, wph, pos);
    k_xt<<<512, 256, 0, stream>>>(x, xt);
    k_qkv<<<384, 256, 0, stream>>>(wqh, xt, qa, ka, va);
    k_attn<<<512, 256, 0, stream>>>(qa, ka, va, pos, op, lp);
    k_proj_ln<<<256, 1024, 0, stream>>>(wph, op, lp, x, b_proj, gamma, beta, (float*)d_out);
}

// Round 7
// 139.873 us; speedup vs baseline: 1.5446x; 1.0798x over previous
//
#include <hip/hip_runtime.h>
#include <hip/hip_bf16.h>
#include <math.h>

#define HW 4096
#define LN_EPS 1e-5f

typedef _Float16 half4v __attribute__((ext_vector_type(4)));
typedef _Float16 half8v __attribute__((ext_vector_type(8)));
typedef float float4v __attribute__((ext_vector_type(4)));
typedef __fp16 fp16v2 __attribute__((ext_vector_type(2)));
typedef __fp16 fp16v4 __attribute__((ext_vector_type(4)));

#if __has_builtin(__builtin_amdgcn_exp2f)
#define EXP2F(x) __builtin_amdgcn_exp2f(x)
#else
#define EXP2F(x) exp2f(x)
#endif

__device__ __forceinline__ half4v lo4(half8v v) { return __builtin_shufflevector(v, v, 0, 1, 2, 3); }
__device__ __forceinline__ half4v hi4(half8v v) { return __builtin_shufflevector(v, v, 4, 5, 6, 7); }

// async global->LDS: each lane deposits 16B at ldsbase + lane*16
__device__ __forceinline__ void gload_lds16(const _Float16* g, _Float16* l) {
#if __has_builtin(__builtin_amdgcn_global_load_lds)
    __builtin_amdgcn_global_load_lds(
        (const __attribute__((address_space(1))) void*)(const void*)g,
        (__attribute__((address_space(3))) void*)(void*)l, 16, 0, 0);
#else
    int lane = threadIdx.x & 63;
    *(half8v*)(l + lane * 8) = *(const half8v*)g;
#endif
}

// ---------------- kernel 1: prep (weights f16 + pos bilinear) AND x transpose ----------
__global__ __launch_bounds__(256) void k_pre(const float* __restrict__ x,
                                             const float* __restrict__ wq,
                                             const float* __restrict__ wp,
                                             const float* __restrict__ pb,
                                             _Float16* __restrict__ xt,
                                             _Float16* __restrict__ wqh,
                                             _Float16* __restrict__ wph,
                                             float* __restrict__ pos) {
    int bx = blockIdx.x, t = threadIdx.x;
    if (bx < 512) { // transpose x [512][4096] f32 -> xt [4096][512] f16
        __shared__ _Float16 tile[64][65];
        int c0 = (bx >> 6) * 64, p0 = (bx & 63) * 64;
        int w = t >> 6, lane = t & 63;
        #pragma unroll
        for (int r = 0; r < 16; r++)
            tile[w * 16 + r][lane] = (_Float16)x[(c0 + w * 16 + r) * HW + p0 + lane];
        __syncthreads();
        int cg = (t & 15) * 4, pr = t >> 4;
        #pragma unroll
        for (int r = 0; r < 4; r++) {
            int p = pr + r * 16;
            half4v v;
            #pragma unroll
            for (int k = 0; k < 4; k++) v[k] = tile[cg + k][p];
            *(half4v*)&xt[(p0 + p) * 512 + c0 + cg] = v;
        }
        return;
    }
    int i = (bx - 512) * 256 + t;
    const float qs = 0.17677669529663687f * 1.4426950408889634f; // scale * log2(e)
    if (i < 49152) { // wq: 768*512/8 chunks; Q rows pre-scaled
        float s = (i < 16384) ? qs : 1.0f;
        float4v a = *(const float4v*)(wq + i * 8);
        float4v b = *(const float4v*)(wq + i * 8 + 4);
        half8v h;
        #pragma unroll
        for (int k = 0; k < 4; k++) { h[k] = (_Float16)(a[k] * s); h[4 + k] = (_Float16)(b[k] * s); }
        *(half8v*)(wqh + i * 8) = h;
    } else if (i < 65536) { // wp
        int j = i - 49152;
        float4v a = *(const float4v*)(wp + j * 8);
        float4v b = *(const float4v*)(wp + j * 8 + 4);
        half8v h;
        #pragma unroll
        for (int k = 0; k < 4; k++) { h[k] = (_Float16)a[k]; h[4 + k] = (_Float16)b[k]; }
        *(half8v*)(wph + j * 8) = h;
    } else { // pos bilinear 16->64, times log2(e)
        int j = i - 65536;
        int h = j >> 12, p = j & 4095, y = p >> 6, xx = p & 63;
        float sy = y * 0.25f - 0.375f, sx = xx * 0.25f - 0.375f;
        float fy = floorf(sy), fx = floorf(sx);
        float wy = sy - fy, wx = sx - fx;
        int y0 = (int)fy, x0 = (int)fx;
        int y1 = y0 + 1 < 15 ? y0 + 1 : 15;
        int x1 = x0 + 1 < 15 ? x0 + 1 : 15;
        y0 = y0 > 0 ? y0 : 0;
        x0 = x0 > 0 ? x0 : 0;
        const float* src = pb + h * 256;
        float v = (1.f - wy) * ((1.f - wx) * src[y0 * 16 + x0] + wx * src[y0 * 16 + x1]) +
                  wy * ((1.f - wx) * src[y1 * 16 + x0] + wx * src[y1 * 16 + x1]);
        pos[j] = v * 1.4426950408889634f;
    }
}

// ---------------- kernel 2: QKV GEMM, LDS-free, 64n x 128p tiles ----------------------
// Outputs: qa [h][q][d] row-major; ka/va as raw MFMA fragment streams per 16-j window:
//   ka: [h][j>>4][lane=(d>>3)*16+(j&15)][idx=d&7]
//   va: [h][j>>4][lane=((j>>2)&3)*16+(d&15)][idx=(d>>4)*4+(j&3)]
__global__ __launch_bounds__(256) void k_qkv(const _Float16* __restrict__ wqh,
                                             const _Float16* __restrict__ xt,
                                             _Float16* __restrict__ qa,
                                             _Float16* __restrict__ ka,
                                             _Float16* __restrict__ va) {
    int n0 = (blockIdx.x >> 5) * 64;
    int p0 = (blockIdx.x & 31) * 128;
    int t = threadIdx.x, w = t >> 6, lane = t & 63, quad = lane >> 4, l16 = lane & 15;

    const _Float16* aptr0 = xt + (p0 + w * 16 + l16) * 512 + quad * 8;
    const _Float16* aptr1 = aptr0 + 64 * 512;
    const _Float16* bptr = wqh + (n0 + l16) * 512 + quad * 8;

    float4v acc[2][4] = {};
    #pragma unroll 4
    for (int kc = 0; kc < 16; kc++) {
        half8v a0 = *(const half8v*)(aptr0 + kc * 32);
        half8v a1 = *(const half8v*)(aptr1 + kc * 32);
        #pragma unroll
        for (int nt = 0; nt < 4; nt++) {
            half8v b = *(const half8v*)(bptr + nt * 16 * 512 + kc * 32);
            acc[0][nt] = __builtin_amdgcn_mfma_f32_16x16x32_f16(a0, b, acc[0][nt], 0, 0, 0);
            acc[1][nt] = __builtin_amdgcn_mfma_f32_16x16x32_f16(a1, b, acc[1][nt], 0, 0, 0);
        }
    }
    #pragma unroll
    for (int ps = 0; ps < 2; ps++) {
        #pragma unroll
        for (int nt = 0; nt < 4; nt++) {
            int o = n0 + nt * 16 + l16;
            #pragma unroll
            for (int r = 0; r < 4; r++) {
                int p = p0 + ps * 64 + w * 16 + quad * 4 + r;
                _Float16 v = (_Float16)acc[ps][nt][r];
                if (o < 256) {
                    qa[(o >> 5) * 131072 + p * 32 + (o & 31)] = v;
                } else if (o < 512) {
                    int oc = o - 256, hh = oc >> 5, d = oc & 31;
                    ka[hh * 131072 + (p >> 4) * 512 + ((d >> 3) * 16 + (p & 15)) * 8 + (d & 7)] = v;
                } else {
                    int oc = o - 512, hh = oc >> 5, d = oc & 31;
                    va[hh * 131072 + (p >> 4) * 512 + (((p >> 2) & 3) * 16 + (d & 15)) * 8 +
                       (d >> 4) * 4 + (p & 3)] = v;
                }
            }
        }
    }
}

// ---------------- kernel 3: flash attention, async-LDS double buffer, j-split x4 -------
// grid 1024 = 8 heads x 4 j-quarters x 32 q-blocks; block = 128 q (4 waves x 32 q).
__global__ __launch_bounds__(256, 4) void k_attn(const _Float16* __restrict__ qa,
                                                 const _Float16* __restrict__ ka,
                                                 const _Float16* __restrict__ va,
                                                 const float* __restrict__ pos,
                                                 float* __restrict__ op,
                                                 float* __restrict__ lp) {
    __shared__ __attribute__((aligned(16))) _Float16 kbuf[2][2048];
    __shared__ __attribute__((aligned(16))) _Float16 vbuf[2][2048];
    __shared__ __attribute__((aligned(16))) float posl[1024];
    int h = blockIdx.x & 7;
    int jq = (blockIdx.x >> 3) & 3;
    int qb = blockIdx.x >> 5;
    int t = threadIdx.x, w = t >> 6, lane = t & 63, quad = lane >> 4, l16 = lane & 15;
    int q0 = qb * 128 + w * 32;

    float* opp = op + jq * 1048576;
    float* lpp = lp + jq * 32768;

    // stage pos quarter (1024 floats)
    *(float4v*)(posl + t * 4) = *(const float4v*)(pos + h * HW + jq * 1024 + t * 4);

    half8v qf0 = *(const half8v*)(qa + h * 131072 + (q0 + l16) * 32 + quad * 8);
    half8v qf1 = *(const half8v*)(qa + h * 131072 + (q0 + 16 + l16) * 32 + quad * 8);

    const _Float16* kg = ka + h * 131072 + jq * 32768;
    const _Float16* vg = va + h * 131072 + jq * 32768;

    // issue tile 0 loads (async into LDS)
    gload_lds16(kg + (w * 64 + lane) * 8, &kbuf[0][w * 512]);
    gload_lds16(vg + (w * 64 + lane) * 8, &vbuf[0][w * 512]);

    float4v o00 = {}, o01 = {}, o10 = {}, o11 = {};
    float lsum0 = 0.f, lsum1 = 0.f;
    const fp16v2 one2 = {(__fp16)1.0f, (__fp16)1.0f};

    for (int tile = 0; tile < 16; tile++) {
        int buf = tile & 1;
        __syncthreads(); // drains this tile's async loads (vmcnt) + prior LDS reads
        if (tile + 1 < 16) {
            gload_lds16(kg + (tile + 1) * 2048 + (w * 64 + lane) * 8, &kbuf[buf ^ 1][w * 512]);
            gload_lds16(vg + (tile + 1) * 2048 + (w * 64 + lane) * 8, &vbuf[buf ^ 1][w * 512]);
        }
        #pragma unroll
        for (int w16 = 0; w16 < 4; w16++) {
            half8v kf = *(const half8v*)(kbuf[buf] + w16 * 512 + lane * 8);
            half8v vf = *(const half8v*)(vbuf[buf] + w16 * 512 + lane * 8);
            float4v pbv = *(const float4v*)(posl + tile * 64 + w16 * 16 + quad * 4);

            // S^T (rows j, cols q); pos[j] pre-added via C operand
            float4v s0 = __builtin_amdgcn_mfma_f32_16x16x32_f16(kf, qf0, pbv, 0, 0, 0);
            float4v s1 = __builtin_amdgcn_mfma_f32_16x16x32_f16(kf, qf1, pbv, 0, 0, 0);

            float e0 = EXP2F(s0[0]);
            float e1 = EXP2F(s0[1]);
            float e2 = EXP2F(s0[2]);
            float e3 = EXP2F(s0[3]);
            float f0 = EXP2F(s1[0]);
            float f1 = EXP2F(s1[1]);
            float f2 = EXP2F(s1[2]);
            float f3 = EXP2F(s1[3]);

            fp16v2 a01 = __builtin_amdgcn_cvt_pkrtz(e0, e1);
            fp16v2 a23 = __builtin_amdgcn_cvt_pkrtz(e2, e3);
            fp16v2 b01 = __builtin_amdgcn_cvt_pkrtz(f0, f1);
            fp16v2 b23 = __builtin_amdgcn_cvt_pkrtz(f2, f3);
            half4v pa0 = __builtin_bit_cast(half4v, __builtin_shufflevector(a01, a23, 0, 1, 2, 3));
            half4v pa1 = __builtin_bit_cast(half4v, __builtin_shufflevector(b01, b23, 0, 1, 2, 3));

#if __has_builtin(__builtin_amdgcn_fdot2)
            lsum0 = __builtin_amdgcn_fdot2(a01, one2, lsum0, false);
            lsum0 = __builtin_amdgcn_fdot2(a23, one2, lsum0, false);
            lsum1 = __builtin_amdgcn_fdot2(b01, one2, lsum1, false);
            lsum1 = __builtin_amdgcn_fdot2(b23, one2, lsum1, false);
#else
            lsum0 += (e0 + e1) + (e2 + e3);
            lsum1 += (f0 + f1) + (f2 + f3);
#endif
            o00 = __builtin_amdgcn_mfma_f32_16x16x16f16(pa0, lo4(vf), o00, 0, 0, 0);
            o01 = __builtin_amdgcn_mfma_f32_16x16x16f16(pa0, hi4(vf), o01, 0, 0, 0);
            o10 = __builtin_amdgcn_mfma_f32_16x16x16f16(pa1, lo4(vf), o10, 0, 0, 0);
            o11 = __builtin_amdgcn_mfma_f32_16x16x16f16(pa1, hi4(vf), o11, 0, 0, 0);
        }
    }
    lsum0 += __shfl_xor(lsum0, 16, 64);
    lsum0 += __shfl_xor(lsum0, 32, 64);
    lsum1 += __shfl_xor(lsum1, 16, 64);
    lsum1 += __shfl_xor(lsum1, 32, 64);
    #pragma unroll
    for (int r = 0; r < 4; r++) {
        int qr = quad * 4 + r;
        int qi0 = q0 + qr, qi1 = q0 + 16 + qr;
        opp[qi0 * 256 + h * 32 + l16] = o00[r];
        opp[qi0 * 256 + h * 32 + 16 + l16] = o01[r];
        opp[qi1 * 256 + h * 32 + l16] = o10[r];
        opp[qi1 * 256 + h * 32 + 16 + l16] = o11[r];
    }
    if (quad == 0) {
        lpp[(q0 + l16) * 8 + h] = lsum0;
        lpp[(q0 + 16 + l16) * 8 + h] = lsum1;
    }
}

// ---------------- kernel 4: combine 4 partials + proj GEMM + residual + LayerNorm ------
__global__ __launch_bounds__(1024) void k_proj_ln(const _Float16* __restrict__ wph,
                                                  const float* __restrict__ op,
                                                  const float* __restrict__ lp,
                                                  const float* __restrict__ x,
                                                  const float* __restrict__ b_proj,
                                                  const float* __restrict__ gamma,
                                                  const float* __restrict__ beta,
                                                  float* __restrict__ out) {
    __shared__ __attribute__((aligned(16))) _Float16 ys[16 * 264];
    __shared__ float red[2][16][17];
    int p0 = blockIdx.x * 16;
    int t = threadIdx.x, w = t >> 6, lane = t & 63, quad = lane >> 4, l16 = lane & 15;
    {
        int p = t >> 6, cg = (t & 63) * 4;
        int pi = p0 + p;
        float4v a0 = *(const float4v*)(op + pi * 256 + cg);
        float4v a1 = *(const float4v*)(op + 1048576 + pi * 256 + cg);
        float4v a2 = *(const float4v*)(op + 2097152 + pi * 256 + cg);
        float4v a3 = *(const float4v*)(op + 3145728 + pi * 256 + cg);
        int hh = cg >> 5;
        float l = lp[pi * 8 + hh] + lp[32768 + pi * 8 + hh] +
                  lp[65536 + pi * 8 + hh] + lp[98304 + pi * 8 + hh];
        float inv = 1.f / l;
        half4v y;
        #pragma unroll
        for (int k = 0; k < 4; k++) y[k] = (_Float16)(((a0[k] + a1[k]) + (a2[k] + a3[k])) * inv);
        *(half4v*)(ys + p * 264 + cg) = y;
    }
    __syncthreads();
    float4v acc[2] = {};
    #pragma unroll
    for (int kc = 0; kc < 8; kc++) {
        half8v b = *(const half8v*)(ys + l16 * 264 + kc * 32 + quad * 8);
        #pragma unroll
        for (int mt = 0; mt < 2; mt++) {
            half8v a = *(const half8v*)(wph + (w * 32 + mt * 16 + l16) * 256 + kc * 32 + quad * 8);
            acc[mt] = __builtin_amdgcn_mfma_f32_16x16x32_f16(a, b, acc[mt], 0, 0, 0);
        }
    }
    int p = p0 + l16;
    float sum = 0.f, sumsq = 0.f;
    #pragma unroll
    for (int mt = 0; mt < 2; mt++)
        #pragma unroll
        for (int r = 0; r < 4; r++) {
            int c = w * 32 + mt * 16 + quad * 4 + r;
            float v = acc[mt][r] + b_proj[c] + x[c * HW + p];
            acc[mt][r] = v;
            sum += v;
            sumsq += v * v;
        }
    sum += __shfl_xor(sum, 16, 64);
    sum += __shfl_xor(sum, 32, 64);
    sumsq += __shfl_xor(sumsq, 16, 64);
    sumsq += __shfl_xor(sumsq, 32, 64);
    if (quad == 0) { red[0][w][l16] = sum; red[1][w][l16] = sumsq; }
    __syncthreads();
    float s0 = 0.f, s1 = 0.f;
    #pragma unroll
    for (int ww = 0; ww < 16; ww++) { s0 += red[0][ww][l16]; s1 += red[1][ww][l16]; }
    float mean = s0 * (1.f / 512.f);
    float var = s1 * (1.f / 512.f) - mean * mean;
    float rstd = rsqrtf(var + LN_EPS);
    #pragma unroll
    for (int mt = 0; mt < 2; mt++)
        #pragma unroll
        for (int r = 0; r < 4; r++) {
            int c = w * 32 + mt * 16 + quad * 4 + r;
            out[c * HW + p] = (acc[mt][r] - mean) * rstd * gamma[c] + beta[c];
        }
}

extern "C" void kernel_launch(void* const* d_in, const int* in_sizes, int n_in,
                              void* d_out, int out_size, void* d_ws, size_t ws_size,
                              hipStream_t stream) {
    const float* x      = (const float*)d_in[0];
    const float* w_qkv  = (const float*)d_in[1];
    const float* w_proj = (const float*)d_in[2];
    const float* b_proj = (const float*)d_in[3];
    const float* pos_b  = (const float*)d_in[4];
    const float* gamma  = (const float*)d_in[5];
    const float* beta   = (const float*)d_in[6];
    char* ws = (char*)d_ws;
    _Float16* xt  = (_Float16*)(ws);              // 4096*512*2     = 4194304
    _Float16* qa  = (_Float16*)(ws + 4194304);    // 2097152
    _Float16* ka  = (_Float16*)(ws + 6291456);    // 2097152
    _Float16* va  = (_Float16*)(ws + 8388608);    // 2097152
    float*    op  = (float*)   (ws + 10485760);   // 4*4096*256*4   = 16777216
    float*    lp  = (float*)   (ws + 27262976);   // 4*4096*8*4     = 524288
    float*    pos = (float*)   (ws + 27787264);   // 131072
    _Float16* wqh = (_Float16*)(ws + 27918336);   // 786432
    _Float16* wph = (_Float16*)(ws + 28704768);   // 262144

    k_pre<<<896, 256, 0, stream>>>(x, w_qkv, w_proj, pos_b, xt, wqh, wph, pos);
    k_qkv<<<384, 256, 0, stream>>>(wqh, xt, qa, ka, va);
    k_attn<<<1024, 256, 0, stream>>>(qa, ka, va, pos, op, lp);
    k_proj_ln<<<256, 1024, 0, stream>>>(wph, op, lp, x, b_proj, gamma, beta, (float*)d_out);
}